// Round 5
// baseline (410.717 us; speedup 1.0000x reference)
//
#include <hip/hip_runtime.h>
#include <hip/hip_cooperative_groups.h>

namespace cg = cooperative_groups;

constexpr int NB    = 8;     // batches
constexpr int NN    = 256;   // sequence length
constexpr int F0    = 512;
constexpr int F1    = 256;
constexpr int F2    = 128;
constexpr int ROWS  = NB * NN;   // 2048
constexpr int KMAX  = 30;
constexpr float INF = 1e30f;

// ---------------- shared-memory overlay for the cooperative mega kernel --------
struct SmGemm { float As[16][64]; float Bs[16][64]; };   //  8 KB (gemm/corr/mp)
struct SmScan { double sd[32][NN]; };                    // 64 KB
struct SmDs   { double P[8][NN]; double diag[NN]; };     // 18 KB
union  SMem   { SmGemm g; SmScan s; SmDs d; };           // 64 KB

// ---------------- fp32 GEMM body: C = act(A @ B + bias), 64x32 tile, BK=16 -----
__device__ __forceinline__ void gemm_body(
    SmGemm& sg, const float* __restrict__ A, const float* __restrict__ B,
    const float* __restrict__ bias, float* __restrict__ C,
    int Ncols, int K, int relu, int rowBase, int colBase)
{
  const int tid = threadIdx.x;
  const int tx = tid & 15;       // col group  (2 cols)
  const int ty = tid >> 4;       // row group  (4 rows)
  float acc[4][2] = {};
  for (int k0 = 0; k0 < K; k0 += 16) {
    {
      const int r  = tid >> 2;
      const int kq = (tid & 3) << 2;
      const float4 av = *(const float4*)(A + (size_t)(rowBase + r) * K + (k0 + kq));
      sg.As[kq+0][r] = av.x; sg.As[kq+1][r] = av.y;
      sg.As[kq+2][r] = av.z; sg.As[kq+3][r] = av.w;
      const int kr = tid >> 4;
      const int c2 = (tid & 15) << 1;
      const float2 bv = *(const float2*)(B + (size_t)(k0 + kr) * Ncols + (colBase + c2));
      sg.Bs[kr][c2+0] = bv.x; sg.Bs[kr][c2+1] = bv.y;
    }
    __syncthreads();
    #pragma unroll
    for (int kk = 0; kk < 16; kk++) {
      const float4 a = *(const float4*)&sg.As[kk][ty*4];
      const float b0v = sg.Bs[kk][tx*2+0];
      const float b1v = sg.Bs[kk][tx*2+1];
      acc[0][0] += a.x*b0v; acc[0][1] += a.x*b1v;
      acc[1][0] += a.y*b0v; acc[1][1] += a.y*b1v;
      acc[2][0] += a.z*b0v; acc[2][1] += a.z*b1v;
      acc[3][0] += a.w*b0v; acc[3][1] += a.w*b1v;
    }
    __syncthreads();
  }
  #pragma unroll
  for (int i = 0; i < 4; i++) {
    const int rr = rowBase + ty*4 + i;
    #pragma unroll
    for (int j = 0; j < 2; j++) {
      const int cc = colBase + tx*2 + j;
      float v = acc[i][j] + bias[cc];
      if (relu) v = fmaxf(v, 0.0f);
      C[(size_t)rr * Ncols + cc] = v;
    }
  }
}

// ---------------- corr body: D[n,m] = 0.5*(1 - z_n.z_m / sqrt(|z_n|^2|z_m|^2)) --
__device__ __forceinline__ void corr_body(
    SmGemm& sg, const float* __restrict__ zb, float* __restrict__ Db,
    int rowBase, int colBase)
{
  const int tid = threadIdx.x;
  const int tx = tid & 15;
  const int ty = tid >> 4;
  float acc[4][4] = {};
  float nsr[4] = {}, nsc[4] = {};
  for (int k0 = 0; k0 < F2; k0 += 16) {
    {
      const int r  = tid >> 2;
      const int kq = (tid & 3) << 2;
      const float4 av = *(const float4*)(zb + (size_t)(rowBase + r) * F2 + (k0 + kq));
      sg.As[kq+0][r] = av.x; sg.As[kq+1][r] = av.y;
      sg.As[kq+2][r] = av.z; sg.As[kq+3][r] = av.w;
      const float4 bv = *(const float4*)(zb + (size_t)(colBase + r) * F2 + (k0 + kq));
      sg.Bs[kq+0][r] = bv.x; sg.Bs[kq+1][r] = bv.y;
      sg.Bs[kq+2][r] = bv.z; sg.Bs[kq+3][r] = bv.w;
    }
    __syncthreads();
    #pragma unroll
    for (int kk = 0; kk < 16; kk++) {
      const float4 a = *(const float4*)&sg.As[kk][ty*4];
      const float4 bq = *(const float4*)&sg.Bs[kk][tx*4];
      const float ar[4] = {a.x, a.y, a.z, a.w};
      const float br[4] = {bq.x, bq.y, bq.z, bq.w};
      #pragma unroll
      for (int i = 0; i < 4; i++) { nsr[i] += ar[i]*ar[i]; nsc[i] += br[i]*br[i]; }
      #pragma unroll
      for (int i = 0; i < 4; i++)
        #pragma unroll
        for (int j = 0; j < 4; j++)
          acc[i][j] += ar[i] * br[j];
    }
    __syncthreads();
  }
  #pragma unroll
  for (int i = 0; i < 4; i++) {
    const int rr = rowBase + ty*4 + i;
    #pragma unroll
    for (int j = 0; j < 4; j++) {
      const int cc = colBase + tx*4 + j;
      const float denom = sqrtf(fmaxf(nsr[i] * nsc[j], 1e-8f));
      Db[(size_t)rr * NN + cc] = 0.5f * (1.0f - acc[i][j] / denom);
    }
  }
}

// ---------------- fused row scan + slab column scan body ------------------------
__device__ __forceinline__ void scan_body(
    SmScan& ss, const float* __restrict__ D, double* __restrict__ S,
    double* __restrict__ aux, int b, int s)
{
  const int tid = threadIdx.x;
  const int wave = tid >> 6, lane = tid & 63;
  for (int t = 0; t < 8; t++) {
    const int rl = wave * 8 + t;
    const float4 dv = *(const float4*)(D + (size_t)(b * NN + s * 32 + rl) * NN + lane * 4);
    double d0 = dv.x, d1 = dv.y, d2 = dv.z, d3 = dv.w;
    double p0 = d0, p1 = p0 + d1, p2 = p1 + d2, p3 = p2 + d3;
    double tt = p3;
    #pragma unroll
    for (int d = 1; d < 64; d <<= 1) {
      double u = __shfl_up(tt, d);
      if (lane >= d) tt += u;
    }
    const double off = tt - p3;
    ss.sd[rl][lane*4+0] = off + p0; ss.sd[rl][lane*4+1] = off + p1;
    ss.sd[rl][lane*4+2] = off + p2; ss.sd[rl][lane*4+3] = off + p3;
  }
  __syncthreads();
  const int j = tid;
  double* Sp = S + (size_t)b * NN * NN + (size_t)(s * 32) * NN + j;
  double sum = 0.0;
  for (int r = 0; r < 32; r += 8) {
    double v0 = ss.sd[r+0][j], v1 = ss.sd[r+1][j], v2 = ss.sd[r+2][j], v3 = ss.sd[r+3][j];
    double v4 = ss.sd[r+4][j], v5 = ss.sd[r+5][j], v6 = ss.sd[r+6][j], v7 = ss.sd[r+7][j];
    v0 += sum; v1 += v0; v2 += v1; v3 += v2; v4 += v3; v5 += v4; v6 += v5; v7 += v6;
    Sp[(size_t)(r+0)*NN] = v0; Sp[(size_t)(r+1)*NN] = v1;
    Sp[(size_t)(r+2)*NN] = v2; Sp[(size_t)(r+3)*NN] = v3;
    Sp[(size_t)(r+4)*NN] = v4; Sp[(size_t)(r+5)*NN] = v5;
    Sp[(size_t)(r+6)*NN] = v6; Sp[(size_t)(r+7)*NN] = v7;
    sum = v7;
  }
  aux[((size_t)b * 8 + s) * NN + j] = sum;
}

// ---------------- Ds -> A body (slab-local S + cross-slab prefixes) -------------
__device__ __forceinline__ void ds_body(
    SmDs& sd_, const double* __restrict__ S, const double* __restrict__ aux,
    float* __restrict__ A, float* __restrict__ Cstk, float* __restrict__ out,
    int slab, int b)
{
  const double* Sb = S + (size_t)b * NN * NN;
  float* Ab = A + (size_t)b * NN * NN;
  const int tid = threadIdx.x;
  const int w = tid >> 6, lane = tid & 63;
  {
    const double* ax = aux + (size_t)b * 8 * NN + tid;
    double run = 0.0;
    #pragma unroll
    for (int u = 0; u < 8; u++) { sd_.P[u][tid] = run; run += ax[(size_t)u * NN]; }
  }
  __syncthreads();
  sd_.diag[tid] = Sb[(size_t)tid * NN + tid] + sd_.P[tid >> 5][tid];
  __syncthreads();
  #pragma unroll
  for (int t = 0; t < 4; t++) {
    const int n = slab * 16 + w * 4 + t;
    const double snn = (n > 0) ? sd_.diag[n-1] : 0.0;
    const double* srow = Sb + (size_t)(n > 0 ? n-1 : 0) * NN;
    const double* Pr   = sd_.P[(n > 0 ? n-1 : 0) >> 5];
    #pragma unroll
    for (int c = 0; c < 4; c++) {
      const int jx = c * 64 + lane;
      float ds = INF;
      if (jx >= n) {
        const double sv = (n > 0) ? (srow[jx] + Pr[jx]) : 0.0;
        ds = (float)(sd_.diag[jx] - 2.0 * sv + snn);
      }
      if (jx < NN - 1) Ab[(size_t)n * NN + jx + 1] = ds;
      else             Cstk[(size_t)b * 32 * NN + n] = ds;   // Ds[n][N-1]
      if (jx == 0)     Ab[(size_t)n * NN + 0] = INF;
    }
  }
  if (slab == 0) out[b * NN + tid] = (tid == NN - 1) ? 1.0f : 0.0f;
}

// ---------------- min-plus MM body: 64x64 tile (upper-tri aware) ----------------
__device__ __forceinline__ void mp_body(
    SmGemm& sg, const float* __restrict__ Pb, const float* __restrict__ Qb,
    float* __restrict__ Cb, int rowBase, int colBase)
{
  const int tid = threadIdx.x;
  const int tx = tid & 15;
  const int ty = tid >> 4;
  if (colBase < rowBase) {             // strictly-lower tile: all INF
    #pragma unroll
    for (int i = 0; i < 4; i++)
      #pragma unroll
      for (int j = 0; j < 4; j++)
        Cb[(size_t)(rowBase + ty*4 + i) * NN + (colBase + tx*4 + j)] = INF;
    return;
  }
  float acc[4][4];
  #pragma unroll
  for (int i = 0; i < 4; i++)
    #pragma unroll
    for (int j = 0; j < 4; j++) acc[i][j] = INF;
  const int kHi = (colBase + 64 < NN) ? colBase + 64 : NN;
  for (int k0 = rowBase; k0 < kHi; k0 += 16) {
    {
      const int r  = tid >> 2;
      const int kq = (tid & 3) << 2;
      const float4 av = *(const float4*)(Pb + (size_t)(rowBase + r) * NN + (k0 + kq));
      sg.As[kq+0][r] = av.x; sg.As[kq+1][r] = av.y;
      sg.As[kq+2][r] = av.z; sg.As[kq+3][r] = av.w;
      const int kr = tid >> 4;
      const int c4 = (tid & 15) << 2;
      const float4 bv = *(const float4*)(Qb + (size_t)(k0 + kr) * NN + (colBase + c4));
      sg.Bs[kr][c4+0] = bv.x; sg.Bs[kr][c4+1] = bv.y;
      sg.Bs[kr][c4+2] = bv.z; sg.Bs[kr][c4+3] = bv.w;
    }
    __syncthreads();
    #pragma unroll
    for (int kk = 0; kk < 16; kk++) {
      const float4 a = *(const float4*)&sg.As[kk][ty*4];
      const float4 bq = *(const float4*)&sg.Bs[kk][tx*4];
      const float ar[4] = {a.x, a.y, a.z, a.w};
      const float br[4] = {bq.x, bq.y, bq.z, bq.w};
      #pragma unroll
      for (int i = 0; i < 4; i++)
        #pragma unroll
        for (int j = 0; j < 4; j++)
          acc[i][j] = fminf(acc[i][j], ar[i] + br[j]);
    }
    __syncthreads();
  }
  #pragma unroll
  for (int i = 0; i < 4; i++)
    #pragma unroll
    for (int j = 0; j < 4; j++)
      Cb[(size_t)(rowBase + ty*4 + i) * NN + (colBase + tx*4 + j)] =
          fminf(acc[i][j], INF);
}

// ---------------- cooperative mega kernel: 7 phases, 6 grid syncs ---------------
// Replaces 7 dispatches (~7-9 us boundary each) with grid.sync (~2-3 us each).
// All phase bodies are verbatim from the previous proven kernels; only the
// blockIdx mapping changed. Inactive blocks fall through to the sync.
__global__ __launch_bounds__(256) void mega(
    const float* __restrict__ x, const float* __restrict__ W0,
    const float* __restrict__ b0, const float* __restrict__ W1,
    const float* __restrict__ b1, float* __restrict__ h,
    float* __restrict__ z, float* __restrict__ D,
    double* __restrict__ S, double* __restrict__ aux,
    float* __restrict__ A, float* __restrict__ A2,
    float* __restrict__ A4, float* __restrict__ Cstk,
    float* __restrict__ out)
{
  cg::grid_group gg = cg::this_grid();
  __shared__ SMem sm;
  const int vb = blockIdx.x;

  // phase 1: h = relu(x@W0+b0)            grid 8x32 = 256
  gemm_body(sm.g, x, W0, b0, h, F1, F0, 1, (vb >> 3) * 64, (vb & 7) * 32);
  gg.sync();
  // phase 2: z = h@W1+b1                  grid 4x32 = 128
  if (vb < 128)
    gemm_body(sm.g, h, W1, b1, z, F2, F1, 0, (vb >> 2) * 64, (vb & 3) * 32);
  gg.sync();
  // phase 3: D = corr dist                grid 4x4x8 = 128
  if (vb < 128)
    corr_body(sm.g, z + (size_t)(vb >> 4) * NN * F2,
              D + (size_t)(vb >> 4) * NN * NN,
              ((vb >> 2) & 3) * 64, (vb & 3) * 64);
  gg.sync();
  // phase 4: S = slab scans of D          grid 8x8 = 64
  if (vb < 64) scan_body(sm.s, D, S, aux, vb >> 3, vb & 7);
  gg.sync();
  // phase 5: A,Cstk[0],out init           grid 16x8 = 128
  if (vb < 128) ds_body(sm.d, S, aux, A, Cstk, out, vb & 15, vb >> 4);
  gg.sync();
  // phase 6: A2 = A (x) A                 grid 4x4x8 = 128
  if (vb < 128) {
    const size_t mb = (size_t)(vb >> 4) * NN * NN;
    mp_body(sm.g, A + mb, A + mb, A2 + mb, ((vb >> 2) & 3) * 64, (vb & 3) * 64);
  }
  gg.sync();
  // phase 7: A4 = A2 (x) A2               grid 4x4x8 = 128
  if (vb < 128) {
    const size_t mb = (size_t)(vb >> 4) * NN * NN;
    mp_body(sm.g, A2 + mb, A2 + mb, A4 + mb, ((vb >> 2) & 3) * 64, (vb & 3) * 64);
  }
}

// ---------------- full chain C_1..C_29 in one kernel: 1 block/batch ------------
// A4 segment per thread (<=16 float4, statically indexed/masked) is read by ONLY
// that thread across all 7 A4 stages -> held in VGPRs loaded straight from
// global; stages read just the C ring from LDS.
constexpr int CSTR = 260;    // ring stride: 16B-aligned, breaks pow2 banks
constexpr int RING = 8;      // ring depth (power of 2)

template<int W>
__device__ __forceinline__ void mp_stage_g(
    const float* __restrict__ P, size_t mb, int n, int q,
    const float* cs, int kin, float* outm)
{
  const float* Pr = P + mb + (size_t)n * NN + q * 64;
  float m[W];
  #pragma unroll
  for (int v = 0; v < W; v++) m[v] = INF;
  if (q * 64 + 63 > n) {          // chunk contains some j > n (else all INF)
    #pragma unroll 4
    for (int i = 0; i < 16; i++) {
      const float4 a = *(const float4*)(Pr + i * 4);
      #pragma unroll
      for (int v = 0; v < W; v++) {
        const float4 c = *(const float4*)&cs[((kin + v) & (RING-1)) * CSTR + q * 64 + i * 4];
        m[v] = fminf(m[v], fminf(fminf(a.x + c.x, a.y + c.y),
                                 fminf(a.z + c.z, a.w + c.w)));
      }
    }
  }
  #pragma unroll
  for (int v = 0; v < W; v++) {
    m[v] = fminf(m[v], __shfl_xor(m[v], 1));
    m[v] = fminf(m[v], __shfl_xor(m[v], 2));
    outm[v] = fminf(m[v], INF);
  }
}

__global__ __launch_bounds__(1024) void chain_full(
    const float* __restrict__ A, const float* __restrict__ A2,
    const float* __restrict__ A4, float* __restrict__ Cstk)
{
  const int b = blockIdx.x;
  const int tid = threadIdx.x;
  const int n = tid >> 2, q = tid & 3;
  __shared__ __align__(16) float cs[RING * CSTR];    // 8.3 KB (only LDS)
  float* Ck = Cstk + (size_t)b * 32 * NN;
  const size_t mb = (size_t)b * NN * NN;

  const int ga  = n >> 2;
  const int La  = 252 - 4 * ga;        // finite floats in row n from jj0
  const int jj0 = 4 * ga + 4;          // first float4-aligned finite jj

  // ---- prefetch this thread's A4 segment into registers (masked, static idx) --
  float4 areg[16];
  {
    const float* a4r = A4 + mb + (size_t)n * NN + jj0;
    #pragma unroll
    for (int fi = 0; fi < 16; fi++) {
      const int f = 4 * q + 16 * fi;
      if (f < La) areg[fi] = *(const float4*)(a4r + f);
      else        areg[fi] = make_float4(INF, INF, INF, INF);
    }
  }

  if (tid < NN) cs[tid] = Ck[tid];     // ring slot 0 = C0
  __syncthreads();

  float m1[1];
  mp_stage_g<1>(A, mb, n, q, cs, 0, m1);
  if (q == 0) { cs[1 * CSTR + n] = m1[0]; Ck[1 * NN + n] = m1[0]; }
  __syncthreads();

  float m2[2];
  mp_stage_g<2>(A2, mb, n, q, cs, 0, m2);
  if (q == 0) {
    cs[2 * CSTR + n] = m2[0]; Ck[2 * NN + n] = m2[0];
    cs[3 * CSTR + n] = m2[1]; Ck[3 * NN + n] = m2[1];
  }
  __syncthreads();

  for (int t = 0; t < 7; t++) {
    float m4[4];
    #pragma unroll
    for (int v = 0; v < 4; v++) m4[v] = INF;
    const float* c0 = cs + ((4*t + 0) & (RING-1)) * CSTR + jj0 + 4*q;
    const float* c1 = cs + ((4*t + 1) & (RING-1)) * CSTR + jj0 + 4*q;
    const float* c2 = cs + ((4*t + 2) & (RING-1)) * CSTR + jj0 + 4*q;
    const float* c3 = cs + ((4*t + 3) & (RING-1)) * CSTR + jj0 + 4*q;
    #pragma unroll
    for (int fi = 0; fi < 16; fi++) {
      const int f = 4 * q + 16 * fi;
      if (f < La) {
        const float4 a = areg[fi];
        const float4 cA = *(const float4*)(c0 + 16 * fi);
        const float4 cB = *(const float4*)(c1 + 16 * fi);
        const float4 cC = *(const float4*)(c2 + 16 * fi);
        const float4 cD = *(const float4*)(c3 + 16 * fi);
        m4[0] = fminf(m4[0], fminf(fminf(a.x + cA.x, a.y + cA.y),
                                   fminf(a.z + cA.z, a.w + cA.w)));
        m4[1] = fminf(m4[1], fminf(fminf(a.x + cB.x, a.y + cB.y),
                                   fminf(a.z + cB.z, a.w + cB.w)));
        m4[2] = fminf(m4[2], fminf(fminf(a.x + cC.x, a.y + cC.y),
                                   fminf(a.z + cC.z, a.w + cC.w)));
        m4[3] = fminf(m4[3], fminf(fminf(a.x + cD.x, a.y + cD.y),
                                   fminf(a.z + cD.z, a.w + cD.w)));
      }
    }
    #pragma unroll
    for (int v = 0; v < 4; v++) {
      m4[v] = fminf(m4[v], __shfl_xor(m4[v], 1));
      m4[v] = fminf(m4[v], __shfl_xor(m4[v], 2));
      m4[v] = fminf(m4[v], INF);
    }
    if (q == 0) {
      #pragma unroll
      for (int v = 0; v < 4; v++) {
        const int k = 4 * t + 4 + v;
        cs[(k & (RING-1)) * CSTR + n] = m4[v];
        Ck[k * NN + n] = m4[v];
      }
    }
    __syncthreads();
  }
}

// ---------------- fused softmax: row sums (LDS) + column accumulation ----------
__global__ __launch_bounds__(256) void sm_fused(
    const float* __restrict__ A, const float* __restrict__ Cstk,
    float* __restrict__ out)
{
  const int k = blockIdx.x + 1;        // 1..29
  const int b = blockIdx.y;
  const int limit = NN - k;
  const int tid = threadIdx.x;
  const float* Ab  = A + (size_t)b * NN * NN;
  const float* Ckb = Cstk + (size_t)b * 32 * NN;
  __shared__ __align__(16) float cprev[NN];   // C_{k-1}
  __shared__ float ck[NN];                    // C_k
  __shared__ float ivh[NN];                   // 1/s per row
  cprev[tid] = Ckb[(k - 1) * NN + tid];
  ck[tid]    = Ckb[k * NN + tid];
  __syncthreads();
  const int r = tid >> 2, q = tid & 3;
  #pragma unroll
  for (int rg = 0; rg < 4; rg++) {
    const int n = rg * 64 + r;
    const float m = ck[n];
    const float* Ar = Ab + (size_t)n * NN + q * 64;
    float s = 0.f;
    if (q * 64 + 63 > n) {              // chunk has some jj > n
      #pragma unroll 4
      for (int i = 0; i < 16; i++) {
        const float4 a = *(const float4*)(Ar + i * 4);
        const int jj = q * 64 + i * 4;
        const float4 c = *(const float4*)&cprev[jj];
        s += (jj + 0 <= limit) ? __expf(m - a.x - c.x) : 0.f;
        s += (jj + 1 <= limit) ? __expf(m - a.y - c.y) : 0.f;
        s += (jj + 2 <= limit) ? __expf(m - a.z - c.z) : 0.f;
        s += (jj + 3 <= limit) ? __expf(m - a.w - c.w) : 0.f;
      }
    }
    s += __shfl_xor(s, 1);
    s += __shfl_xor(s, 2);
    if (q == 0) ivh[n] = 1.0f / s;
  }
  __syncthreads();
  const int j = tid;
  if (j < limit) {
    const float cj = cprev[j + 1];
    const int nmax = (j < limit - 1) ? j : limit - 1;
    float a = 0.0f;
    #pragma unroll 4
    for (int nr = 0; nr <= nmax; nr++)
      a += __expf(ck[nr] - Ab[(size_t)nr * NN + j + 1] - cj) * ivh[nr];
    int kmaxj = NN - 1 - j; if (kmaxj > KMAX - 1) kmaxj = KMAX - 1;
    const float cnt = (float)((j + 1) * kmaxj);
    atomicAdd(&out[b * NN + j], a / cnt);
  }
}

extern "C" void kernel_launch(void* const* d_in, const int* in_sizes, int n_in,
                              void* d_out, int out_size, void* d_ws, size_t ws_size,
                              hipStream_t stream) {
  const float* x  = (const float*)d_in[0];
  const float* W0 = (const float*)d_in[1];
  const float* b0 = (const float*)d_in[2];
  const float* W1 = (const float*)d_in[3];
  const float* b1 = (const float*)d_in[4];
  float* out = (float*)d_out;

  // ws layout (max 7 MiB + 128 KiB used; ws proven >= 8 MiB):
  //  region        lifetime (phases run in strict order via grid.sync)
  //  h    [0,2M)   ph1 W -> ph2 R
  //  S    [0,4M)   ph4 W (h dead) -> ph5 R       (slab-local scans)
  //  A2   [0,2M)   ph6 W (S dead) -> ph7/chain R
  //  A4   [2M,4M)  ph7 W -> chain R
  //  D    [4M,6M)  ph3 W -> ph4 R
  //  A    [4M,6M)  ph5 W (D dead) -> ph6/chain/sm R
  //  z    [6M,7M)  ph2 W -> ph3 R
  //  Cstk [6M,6.25M) ph5 W (z dead) -> chain RW -> sm R
  //  aux  [7M,7M+128K) ph4 W -> ph5 R
  char* base = (char*)d_ws;
  float*  h    = (float*)(base);
  double* S    = (double*)(base);
  float*  A2   = (float*)(base);
  float*  A4   = (float*)(base + (2u << 20));
  float*  D    = (float*)(base + (4u << 20));
  float*  A    = (float*)(base + (4u << 20));
  float*  z    = (float*)(base + (6u << 20));
  float*  Cstk = (float*)(base + (6u << 20));
  double* aux  = (double*)(base + (7u << 20));

  void* margs[] = {
    (void*)&x, (void*)&W0, (void*)&b0, (void*)&W1, (void*)&b1,
    (void*)&h, (void*)&z, (void*)&D, (void*)&S, (void*)&aux,
    (void*)&A, (void*)&A2, (void*)&A4, (void*)&Cstk, (void*)&out
  };
  hipLaunchCooperativeKernel((const void*)mega, dim3(256), dim3(256),
                             margs, 0, stream);
  chain_full<<<dim3(NB), 1024, 0, stream>>>(A, A2, A4, Cstk);
  sm_fused<<<dim3(KMAX-1, NB), 256, 0, stream>>>(A, Cstk, out);
}

// Round 6
// 267.563 us; speedup vs baseline: 1.5350x; 1.5350x over previous
//
#include <hip/hip_runtime.h>

constexpr int NB    = 8;     // batches
constexpr int NN    = 256;   // sequence length
constexpr int F0    = 512;
constexpr int F1    = 256;
constexpr int F2    = 128;
constexpr int ROWS  = NB * NN;   // 2048
constexpr int KMAX  = 30;
constexpr float INF = 1e30f;

// ---------------- fp32 GEMM: C = act(A @ B + bias), 64x32 tile, BK=16 ----------
__global__ __launch_bounds__(256) void gemm_bias_act(
    const float* __restrict__ A, const float* __restrict__ B,
    const float* __restrict__ bias, float* __restrict__ C,
    int M, int Ncols, int K, int relu)
{
  __shared__ float As[16][64];   // [k][m]
  __shared__ float Bs[16][32];   // [k][n]
  const int tid = threadIdx.x;
  const int tx = tid & 15;       // col group  (2 cols)
  const int ty = tid >> 4;       // row group  (4 rows)
  const int rowBase = blockIdx.y * 64;
  const int colBase = blockIdx.x * 32;
  float acc[4][2] = {};
  for (int k0 = 0; k0 < K; k0 += 16) {
    {
      const int r  = tid >> 2;
      const int kq = (tid & 3) << 2;
      const float4 av = *(const float4*)(A + (size_t)(rowBase + r) * K + (k0 + kq));
      As[kq+0][r] = av.x; As[kq+1][r] = av.y; As[kq+2][r] = av.z; As[kq+3][r] = av.w;
      const int kr = tid >> 4;
      const int c2 = (tid & 15) << 1;
      const float2 bv = *(const float2*)(B + (size_t)(k0 + kr) * Ncols + (colBase + c2));
      Bs[kr][c2+0] = bv.x; Bs[kr][c2+1] = bv.y;
    }
    __syncthreads();
    #pragma unroll
    for (int kk = 0; kk < 16; kk++) {
      const float4 a = *(const float4*)&As[kk][ty*4];
      const float b0v = Bs[kk][tx*2+0];
      const float b1v = Bs[kk][tx*2+1];
      acc[0][0] += a.x*b0v; acc[0][1] += a.x*b1v;
      acc[1][0] += a.y*b0v; acc[1][1] += a.y*b1v;
      acc[2][0] += a.z*b0v; acc[2][1] += a.z*b1v;
      acc[3][0] += a.w*b0v; acc[3][1] += a.w*b1v;
    }
    __syncthreads();
  }
  #pragma unroll
  for (int i = 0; i < 4; i++) {
    const int rr = rowBase + ty*4 + i;
    #pragma unroll
    for (int j = 0; j < 2; j++) {
      const int cc = colBase + tx*2 + j;
      float v = acc[i][j] + bias[cc];
      if (relu) v = fmaxf(v, 0.0f);
      C[(size_t)rr * Ncols + cc] = v;
    }
  }
}

// ---------------- fused corr + scan: one block = (batch, 32-row slab) ----------
// Computes D[32][256] for the slab (identical fp32 ops / k-order as the old
// corr_dist 64x64 tiling), stores it as doubles directly in LDS, then runs the
// identical row-scan + slab column-scan. D never touches global memory and one
// dispatch boundary (~7-8 us) disappears.
__global__ __launch_bounds__(256) void corr_scan(
    const float* __restrict__ z, double* __restrict__ S, double* __restrict__ aux)
{
  const int s = blockIdx.x & 7;
  const int b = blockIdx.x >> 3;
  const int tid = threadIdx.x;
  __shared__ double sd[32][NN];          // 64 KB D slab (as doubles)
  __shared__ float zs[32][F2];           // 16 KB slab rows of z
  __shared__ float Bs[16][64];           //  4 KB column-side k-chunk
  const float* zb = z + (size_t)b * NN * F2;

  // stage slab rows of z (32 x 128 = 1024 float4, 4 per thread)
  {
    const float4* src = (const float4*)(zb + (size_t)(s * 32) * F2);
    float4* dst = (float4*)&zs[0][0];
    #pragma unroll
    for (int i = 0; i < 4; i++) dst[tid + 256 * i] = src[tid + 256 * i];
  }
  __syncthreads();

  const int tx = tid & 15;         // 4 cols per thread
  const int ty = tid >> 4;         // 2 rows per thread
  for (int ct = 0; ct < 4; ct++) {
    const int colBase = ct * 64;
    float acc[2][4] = {};
    float nsr[2] = {}, nsc[4] = {};
    for (int k0 = 0; k0 < F2; k0 += 16) {
      {
        const int c  = tid >> 2;              // 0..63
        const int kq = (tid & 3) << 2;
        const float4 bv = *(const float4*)(zb + (size_t)(colBase + c) * F2 + (k0 + kq));
        Bs[kq+0][c] = bv.x; Bs[kq+1][c] = bv.y; Bs[kq+2][c] = bv.z; Bs[kq+3][c] = bv.w;
      }
      __syncthreads();
      #pragma unroll
      for (int kk = 0; kk < 16; kk++) {
        const float a0 = zs[ty*2+0][k0+kk];
        const float a1 = zs[ty*2+1][k0+kk];
        const float4 bq = *(const float4*)&Bs[kk][tx*4];
        const float br[4] = {bq.x, bq.y, bq.z, bq.w};
        nsr[0] += a0*a0; nsr[1] += a1*a1;
        #pragma unroll
        for (int j = 0; j < 4; j++) nsc[j] += br[j]*br[j];
        #pragma unroll
        for (int j = 0; j < 4; j++) { acc[0][j] += a0*br[j]; acc[1][j] += a1*br[j]; }
      }
      __syncthreads();
    }
    #pragma unroll
    for (int i = 0; i < 2; i++) {
      const int rloc = ty*2 + i;
      #pragma unroll
      for (int j = 0; j < 4; j++) {
        const float denom = sqrtf(fmaxf(nsr[i]*nsc[j], 1e-8f));
        sd[rloc][colBase + tx*4 + j] = (double)(0.5f*(1.0f - acc[i][j]/denom));
      }
    }
  }
  __syncthreads();

  // row-wise fp64 inclusive scan (identical to old scan_slab, source = LDS)
  const int wave = tid >> 6, lane = tid & 63;
  for (int t = 0; t < 8; t++) {
    const int rl = wave * 8 + t;
    double d0 = sd[rl][lane*4+0], d1 = sd[rl][lane*4+1];
    double d2 = sd[rl][lane*4+2], d3 = sd[rl][lane*4+3];
    double p0 = d0, p1 = p0 + d1, p2 = p1 + d2, p3 = p2 + d3;
    double tt = p3;
    #pragma unroll
    for (int d = 1; d < 64; d <<= 1) {
      double u = __shfl_up(tt, d);
      if (lane >= d) tt += u;
    }
    const double off = tt - p3;
    sd[rl][lane*4+0] = off + p0; sd[rl][lane*4+1] = off + p1;
    sd[rl][lane*4+2] = off + p2; sd[rl][lane*4+3] = off + p3;
  }
  __syncthreads();

  // slab column scan -> S (slab-local) + aux (slab totals)
  const int j = tid;
  double* Sp = S + (size_t)b * NN * NN + (size_t)(s * 32) * NN + j;
  double sum = 0.0;
  for (int r = 0; r < 32; r += 8) {
    double v0 = sd[r+0][j], v1 = sd[r+1][j], v2 = sd[r+2][j], v3 = sd[r+3][j];
    double v4 = sd[r+4][j], v5 = sd[r+5][j], v6 = sd[r+6][j], v7 = sd[r+7][j];
    v0 += sum; v1 += v0; v2 += v1; v3 += v2; v4 += v3; v5 += v4; v6 += v5; v7 += v6;
    Sp[(size_t)(r+0)*NN] = v0; Sp[(size_t)(r+1)*NN] = v1;
    Sp[(size_t)(r+2)*NN] = v2; Sp[(size_t)(r+3)*NN] = v3;
    Sp[(size_t)(r+4)*NN] = v4; Sp[(size_t)(r+5)*NN] = v5;
    Sp[(size_t)(r+6)*NN] = v6; Sp[(size_t)(r+7)*NN] = v7;
    sum = v7;
  }
  aux[((size_t)b * 8 + s) * NN + j] = sum;
}

// ---------------- Ds -> A (shifted), C0 -> Cstk[0], out init -------------------
// S holds slab-local scans; cross-slab column offsets P (exclusive prefix of
// aux) are built in LDS and added on the fly: S_full[r][j] = S[r][j]+P[r>>5][j].
// Ds[n,j] (j>=n) = S_full[j][j] - 2*S_full[n-1][j] + S_full[n-1][n-1]
__global__ __launch_bounds__(256) void ds_mat(
    const double* __restrict__ S, const double* __restrict__ aux,
    float* __restrict__ A, float* __restrict__ Cstk, float* __restrict__ out)
{
  const int slab = blockIdx.x;          // 16 rows
  const int b = blockIdx.y;
  const double* Sb = S + (size_t)b * NN * NN;
  float* Ab = A + (size_t)b * NN * NN;
  const int tid = threadIdx.x;
  const int w = tid >> 6, lane = tid & 63;
  __shared__ double P[8][NN];           // 16 KB exclusive column prefixes
  __shared__ double diag[NN];
  {
    const double* ax = aux + (size_t)b * 8 * NN + tid;
    double run = 0.0;
    #pragma unroll
    for (int u = 0; u < 8; u++) { P[u][tid] = run; run += ax[(size_t)u * NN]; }
  }
  __syncthreads();
  diag[tid] = Sb[(size_t)tid * NN + tid] + P[tid >> 5][tid];
  __syncthreads();
  #pragma unroll
  for (int t = 0; t < 4; t++) {
    const int n = slab * 16 + w * 4 + t;
    const double snn = (n > 0) ? diag[n-1] : 0.0;
    const double* srow = Sb + (size_t)(n > 0 ? n-1 : 0) * NN;
    const double* Pr   = P[(n > 0 ? n-1 : 0) >> 5];
    #pragma unroll
    for (int c = 0; c < 4; c++) {
      const int jx = c * 64 + lane;
      float ds = INF;
      if (jx >= n) {
        const double sv = (n > 0) ? (srow[jx] + Pr[jx]) : 0.0;
        ds = (float)(diag[jx] - 2.0 * sv + snn);
      }
      if (jx < NN - 1) Ab[(size_t)n * NN + jx + 1] = ds;
      else             Cstk[(size_t)b * 32 * NN + n] = ds;   // Ds[n][N-1]
      if (jx == 0)     Ab[(size_t)n * NN + 0] = INF;
    }
  }
  if (slab == 0) out[b * NN + tid] = (tid == NN - 1) ? 1.0f : 0.0f;
}

// ---------------- min-plus MM: C = P (x) Q, 64x64 tile, per batch --------------
// P, Q strictly upper triangular (INF below): skip lower tiles + clamp k range.
__global__ __launch_bounds__(256) void mp_mm(
    const float* __restrict__ P, const float* __restrict__ Q, float* __restrict__ Cm)
{
  const int b = blockIdx.z;
  const int tid = threadIdx.x;
  const int tx = tid & 15;
  const int ty = tid >> 4;
  const int rowBase = blockIdx.y * 64;
  const int colBase = blockIdx.x * 64;
  float* Cb = Cm + (size_t)b * NN * NN;
  if (colBase < rowBase) {             // strictly-lower tile: all INF
    #pragma unroll
    for (int i = 0; i < 4; i++)
      #pragma unroll
      for (int j = 0; j < 4; j++)
        Cb[(size_t)(rowBase + ty*4 + i) * NN + (colBase + tx*4 + j)] = INF;
    return;
  }
  const float* Pb = P + (size_t)b * NN * NN;
  const float* Qb = Q + (size_t)b * NN * NN;
  __shared__ float As[16][64];
  __shared__ float Bs[16][64];
  float acc[4][4];
  #pragma unroll
  for (int i = 0; i < 4; i++)
    #pragma unroll
    for (int j = 0; j < 4; j++) acc[i][j] = INF;
  const int kHi = (colBase + 64 < NN) ? colBase + 64 : NN;
  for (int k0 = rowBase; k0 < kHi; k0 += 16) {
    {
      const int r  = tid >> 2;
      const int kq = (tid & 3) << 2;
      const float4 av = *(const float4*)(Pb + (size_t)(rowBase + r) * NN + (k0 + kq));
      As[kq+0][r] = av.x; As[kq+1][r] = av.y; As[kq+2][r] = av.z; As[kq+3][r] = av.w;
      const int kr = tid >> 4;
      const int c4 = (tid & 15) << 2;
      const float4 bv = *(const float4*)(Qb + (size_t)(k0 + kr) * NN + (colBase + c4));
      Bs[kr][c4+0] = bv.x; Bs[kr][c4+1] = bv.y; Bs[kr][c4+2] = bv.z; Bs[kr][c4+3] = bv.w;
    }
    __syncthreads();
    #pragma unroll
    for (int kk = 0; kk < 16; kk++) {
      const float4 a = *(const float4*)&As[kk][ty*4];
      const float4 bq = *(const float4*)&Bs[kk][tx*4];
      const float ar[4] = {a.x, a.y, a.z, a.w};
      const float br[4] = {bq.x, bq.y, bq.z, bq.w};
      #pragma unroll
      for (int i = 0; i < 4; i++)
        #pragma unroll
        for (int j = 0; j < 4; j++)
          acc[i][j] = fminf(acc[i][j], ar[i] + br[j]);
    }
    __syncthreads();
  }
  #pragma unroll
  for (int i = 0; i < 4; i++)
    #pragma unroll
    for (int j = 0; j < 4; j++)
      Cb[(size_t)(rowBase + ty*4 + i) * NN + (colBase + tx*4 + j)] =
          fminf(acc[i][j], INF);
}

// ---------------- full chain C_1..C_29 in one kernel: 1 block/batch ------------
// A4 segment per thread (<=16 float4, statically indexed/masked) is read by ONLY
// that thread across all 7 A4 stages -> held in VGPRs loaded straight from
// global; stages read just the C ring from LDS.
constexpr int CSTR = 260;    // ring stride: 16B-aligned, breaks pow2 banks
constexpr int RING = 8;      // ring depth (power of 2)

template<int W>
__device__ __forceinline__ void mp_stage_g(
    const float* __restrict__ P, size_t mb, int n, int q,
    const float* cs, int kin, float* outm)
{
  const float* Pr = P + mb + (size_t)n * NN + q * 64;
  float m[W];
  #pragma unroll
  for (int v = 0; v < W; v++) m[v] = INF;
  if (q * 64 + 63 > n) {          // chunk contains some j > n (else all INF)
    #pragma unroll 4
    for (int i = 0; i < 16; i++) {
      const float4 a = *(const float4*)(Pr + i * 4);
      #pragma unroll
      for (int v = 0; v < W; v++) {
        const float4 c = *(const float4*)&cs[((kin + v) & (RING-1)) * CSTR + q * 64 + i * 4];
        m[v] = fminf(m[v], fminf(fminf(a.x + c.x, a.y + c.y),
                                 fminf(a.z + c.z, a.w + c.w)));
      }
    }
  }
  #pragma unroll
  for (int v = 0; v < W; v++) {
    m[v] = fminf(m[v], __shfl_xor(m[v], 1));
    m[v] = fminf(m[v], __shfl_xor(m[v], 2));
    outm[v] = fminf(m[v], INF);
  }
}

__global__ __launch_bounds__(1024) void chain_full(
    const float* __restrict__ A, const float* __restrict__ A2,
    const float* __restrict__ A4, float* __restrict__ Cstk)
{
  const int b = blockIdx.x;
  const int tid = threadIdx.x;
  const int n = tid >> 2, q = tid & 3;
  __shared__ __align__(16) float cs[RING * CSTR];    // 8.3 KB (only LDS)
  float* Ck = Cstk + (size_t)b * 32 * NN;
  const size_t mb = (size_t)b * NN * NN;

  const int ga  = n >> 2;
  const int La  = 252 - 4 * ga;        // finite floats in row n from jj0
  const int jj0 = 4 * ga + 4;          // first float4-aligned finite jj

  // ---- prefetch this thread's A4 segment into registers (masked, static idx) --
  float4 areg[16];
  {
    const float* a4r = A4 + mb + (size_t)n * NN + jj0;
    #pragma unroll
    for (int fi = 0; fi < 16; fi++) {
      const int f = 4 * q + 16 * fi;
      if (f < La) areg[fi] = *(const float4*)(a4r + f);
      else        areg[fi] = make_float4(INF, INF, INF, INF);
    }
  }

  if (tid < NN) cs[tid] = Ck[tid];     // ring slot 0 = C0
  __syncthreads();

  float m1[1];
  mp_stage_g<1>(A, mb, n, q, cs, 0, m1);
  if (q == 0) { cs[1 * CSTR + n] = m1[0]; Ck[1 * NN + n] = m1[0]; }
  __syncthreads();

  float m2[2];
  mp_stage_g<2>(A2, mb, n, q, cs, 0, m2);
  if (q == 0) {
    cs[2 * CSTR + n] = m2[0]; Ck[2 * NN + n] = m2[0];
    cs[3 * CSTR + n] = m2[1]; Ck[3 * NN + n] = m2[1];
  }
  __syncthreads();

  for (int t = 0; t < 7; t++) {
    float m4[4];
    #pragma unroll
    for (int v = 0; v < 4; v++) m4[v] = INF;
    const float* c0 = cs + ((4*t + 0) & (RING-1)) * CSTR + jj0 + 4*q;
    const float* c1 = cs + ((4*t + 1) & (RING-1)) * CSTR + jj0 + 4*q;
    const float* c2 = cs + ((4*t + 2) & (RING-1)) * CSTR + jj0 + 4*q;
    const float* c3 = cs + ((4*t + 3) & (RING-1)) * CSTR + jj0 + 4*q;
    #pragma unroll
    for (int fi = 0; fi < 16; fi++) {
      const int f = 4 * q + 16 * fi;
      if (f < La) {
        const float4 a = areg[fi];
        const float4 cA = *(const float4*)(c0 + 16 * fi);
        const float4 cB = *(const float4*)(c1 + 16 * fi);
        const float4 cC = *(const float4*)(c2 + 16 * fi);
        const float4 cD = *(const float4*)(c3 + 16 * fi);
        m4[0] = fminf(m4[0], fminf(fminf(a.x + cA.x, a.y + cA.y),
                                   fminf(a.z + cA.z, a.w + cA.w)));
        m4[1] = fminf(m4[1], fminf(fminf(a.x + cB.x, a.y + cB.y),
                                   fminf(a.z + cB.z, a.w + cB.w)));
        m4[2] = fminf(m4[2], fminf(fminf(a.x + cC.x, a.y + cC.y),
                                   fminf(a.z + cC.z, a.w + cC.w)));
        m4[3] = fminf(m4[3], fminf(fminf(a.x + cD.x, a.y + cD.y),
                                   fminf(a.z + cD.z, a.w + cD.w)));
      }
    }
    #pragma unroll
    for (int v = 0; v < 4; v++) {
      m4[v] = fminf(m4[v], __shfl_xor(m4[v], 1));
      m4[v] = fminf(m4[v], __shfl_xor(m4[v], 2));
      m4[v] = fminf(m4[v], INF);
    }
    if (q == 0) {
      #pragma unroll
      for (int v = 0; v < 4; v++) {
        const int k = 4 * t + 4 + v;
        cs[(k & (RING-1)) * CSTR + n] = m4[v];
        Ck[k * NN + n] = m4[v];
      }
    }
    __syncthreads();
  }
}

// ---------------- fused softmax: row sums (LDS) + column accumulation ----------
__global__ __launch_bounds__(256) void sm_fused(
    const float* __restrict__ A, const float* __restrict__ Cstk,
    float* __restrict__ out)
{
  const int k = blockIdx.x + 1;        // 1..29
  const int b = blockIdx.y;
  const int limit = NN - k;
  const int tid = threadIdx.x;
  const float* Ab  = A + (size_t)b * NN * NN;
  const float* Ckb = Cstk + (size_t)b * 32 * NN;
  __shared__ __align__(16) float cprev[NN];   // C_{k-1}
  __shared__ float ck[NN];                    // C_k
  __shared__ float ivh[NN];                   // 1/s per row
  cprev[tid] = Ckb[(k - 1) * NN + tid];
  ck[tid]    = Ckb[k * NN + tid];
  __syncthreads();
  const int r = tid >> 2, q = tid & 3;
  #pragma unroll
  for (int rg = 0; rg < 4; rg++) {
    const int n = rg * 64 + r;
    const float m = ck[n];
    const float* Ar = Ab + (size_t)n * NN + q * 64;
    float s = 0.f;
    if (q * 64 + 63 > n) {              // chunk has some jj > n
      #pragma unroll 4
      for (int i = 0; i < 16; i++) {
        const float4 a = *(const float4*)(Ar + i * 4);
        const int jj = q * 64 + i * 4;
        const float4 c = *(const float4*)&cprev[jj];
        s += (jj + 0 <= limit) ? __expf(m - a.x - c.x) : 0.f;
        s += (jj + 1 <= limit) ? __expf(m - a.y - c.y) : 0.f;
        s += (jj + 2 <= limit) ? __expf(m - a.z - c.z) : 0.f;
        s += (jj + 3 <= limit) ? __expf(m - a.w - c.w) : 0.f;
      }
    }
    s += __shfl_xor(s, 1);
    s += __shfl_xor(s, 2);
    if (q == 0) ivh[n] = 1.0f / s;
  }
  __syncthreads();
  const int j = tid;
  if (j < limit) {
    const float cj = cprev[j + 1];
    const int nmax = (j < limit - 1) ? j : limit - 1;
    float a = 0.0f;
    #pragma unroll 4
    for (int nr = 0; nr <= nmax; nr++)
      a += __expf(ck[nr] - Ab[(size_t)nr * NN + j + 1] - cj) * ivh[nr];
    int kmaxj = NN - 1 - j; if (kmaxj > KMAX - 1) kmaxj = KMAX - 1;
    const float cnt = (float)((j + 1) * kmaxj);
    atomicAdd(&out[b * NN + j], a / cnt);
  }
}

extern "C" void kernel_launch(void* const* d_in, const int* in_sizes, int n_in,
                              void* d_out, int out_size, void* d_ws, size_t ws_size,
                              hipStream_t stream) {
  const float* x  = (const float*)d_in[0];
  const float* W0 = (const float*)d_in[1];
  const float* b0 = (const float*)d_in[2];
  const float* W1 = (const float*)d_in[3];
  const float* b1 = (const float*)d_in[4];
  float* out = (float*)d_out;

  // ws layout (max 7 MiB + 128 KiB used; ws proven >= 8 MiB):
  //  region        lifetime
  //  h    [0,2M)   gemm1 W -> gemm2 R
  //  S    [0,4M)   corr_scan W (h dead) -> ds_mat R    (slab-local scans)
  //  A2   [0,2M)   mp_mm1 W (S dead) -> mp_mm2/chain R
  //  A4   [2M,4M)  mp_mm2 W -> chain R
  //  A    [4M,6M)  ds_mat W -> mp_mm1/chain/sm R
  //  z    [6M,7M)  gemm2 W -> corr_scan R
  //  Cstk [6M,6.25M) ds_mat W (z dead) -> chain RW -> sm R
  //  aux  [7M,7M+128K) corr_scan W -> ds_mat R
  char* base = (char*)d_ws;
  float*  h    = (float*)(base);
  double* S    = (double*)(base);
  float*  A2   = (float*)(base);
  float*  A4   = (float*)(base + (2u << 20));
  float*  A    = (float*)(base + (4u << 20));
  float*  z    = (float*)(base + (6u << 20));
  float*  Cstk = (float*)(base + (6u << 20));
  double* aux  = (double*)(base + (7u << 20));

  gemm_bias_act<<<dim3(F1/32, ROWS/64), 256, 0, stream>>>(x, W0, b0, h, ROWS, F1, F0, 1);
  gemm_bias_act<<<dim3(F2/32, ROWS/64), 256, 0, stream>>>(h, W1, b1, z, ROWS, F2, F1, 0);
  corr_scan<<<dim3(NB*8), 256, 0, stream>>>(z, S, aux);
  ds_mat<<<dim3(16, NB), 256, 0, stream>>>(S, aux, A, Cstk, out);
  mp_mm<<<dim3(NN/64, NN/64, NB), 256, 0, stream>>>(A, A, A2);
  mp_mm<<<dim3(NN/64, NN/64, NB), 256, 0, stream>>>(A2, A2, A4);
  chain_full<<<dim3(NB), 1024, 0, stream>>>(A, A2, A4, Cstk);
  sm_fused<<<dim3(KMAX-1, NB), 256, 0, stream>>>(A, Cstk, out);
}

// Round 7
// 186.191 us; speedup vs baseline: 2.2059x; 1.4370x over previous
//
#include <hip/hip_runtime.h>

constexpr int NB    = 8;     // batches
constexpr int NN    = 256;   // sequence length
constexpr int F0    = 512;
constexpr int F1    = 256;
constexpr int F2    = 128;
constexpr int ROWS  = NB * NN;   // 2048
constexpr int KMAX  = 30;
constexpr float INF = 1e30f;

// ---------------- fp32 GEMM: C = act(A @ B + bias), 64x32 tile, BK=16 ----------
__global__ __launch_bounds__(256) void gemm_bias_act(
    const float* __restrict__ A, const float* __restrict__ B,
    const float* __restrict__ bias, float* __restrict__ C,
    int M, int Ncols, int K, int relu)
{
  __shared__ float As[16][64];   // [k][m]
  __shared__ float Bs[16][32];   // [k][n]
  const int tid = threadIdx.x;
  const int tx = tid & 15;       // col group  (2 cols)
  const int ty = tid >> 4;       // row group  (4 rows)
  const int rowBase = blockIdx.y * 64;
  const int colBase = blockIdx.x * 32;
  float acc[4][2] = {};
  for (int k0 = 0; k0 < K; k0 += 16) {
    {
      const int r  = tid >> 2;
      const int kq = (tid & 3) << 2;
      const float4 av = *(const float4*)(A + (size_t)(rowBase + r) * K + (k0 + kq));
      As[kq+0][r] = av.x; As[kq+1][r] = av.y; As[kq+2][r] = av.z; As[kq+3][r] = av.w;
      const int kr = tid >> 4;
      const int c2 = (tid & 15) << 1;
      const float2 bv = *(const float2*)(B + (size_t)(k0 + kr) * Ncols + (colBase + c2));
      Bs[kr][c2+0] = bv.x; Bs[kr][c2+1] = bv.y;
    }
    __syncthreads();
    #pragma unroll
    for (int kk = 0; kk < 16; kk++) {
      const float4 a = *(const float4*)&As[kk][ty*4];
      const float b0v = Bs[kk][tx*2+0];
      const float b1v = Bs[kk][tx*2+1];
      acc[0][0] += a.x*b0v; acc[0][1] += a.x*b1v;
      acc[1][0] += a.y*b0v; acc[1][1] += a.y*b1v;
      acc[2][0] += a.z*b0v; acc[2][1] += a.z*b1v;
      acc[3][0] += a.w*b0v; acc[3][1] += a.w*b1v;
    }
    __syncthreads();
  }
  #pragma unroll
  for (int i = 0; i < 4; i++) {
    const int rr = rowBase + ty*4 + i;
    #pragma unroll
    for (int j = 0; j < 2; j++) {
      const int cc = colBase + tx*2 + j;
      float v = acc[i][j] + bias[cc];
      if (relu) v = fmaxf(v, 0.0f);
      C[(size_t)rr * Ncols + cc] = v;
    }
  }
}

// ---------------- D[b,n,m] = 0.5*(1 - (z_n.z_m)/sqrt(max(|z_n|^2|z_m|^2,1e-8)))
// Row/col norms accumulated in registers from the same LDS fragments.
__global__ __launch_bounds__(256) void corr_dist(
    const float* __restrict__ z, float* __restrict__ D)
{
  const int b = blockIdx.z;
  const float* zb = z + (size_t)b * NN * F2;
  __shared__ float As[16][64];  // [k][row]
  __shared__ float Bs[16][64];  // [k][col]
  const int tid = threadIdx.x;
  const int tx = tid & 15;
  const int ty = tid >> 4;
  const int rowBase = blockIdx.y * 64;
  const int colBase = blockIdx.x * 64;
  float acc[4][4] = {};
  float nsr[4] = {}, nsc[4] = {};
  for (int k0 = 0; k0 < F2; k0 += 16) {
    {
      const int r  = tid >> 2;
      const int kq = (tid & 3) << 2;
      const float4 av = *(const float4*)(zb + (size_t)(rowBase + r) * F2 + (k0 + kq));
      As[kq+0][r] = av.x; As[kq+1][r] = av.y; As[kq+2][r] = av.z; As[kq+3][r] = av.w;
      const float4 bv = *(const float4*)(zb + (size_t)(colBase + r) * F2 + (k0 + kq));
      Bs[kq+0][r] = bv.x; Bs[kq+1][r] = bv.y; Bs[kq+2][r] = bv.z; Bs[kq+3][r] = bv.w;
    }
    __syncthreads();
    #pragma unroll
    for (int kk = 0; kk < 16; kk++) {
      const float4 a = *(const float4*)&As[kk][ty*4];
      const float4 bq = *(const float4*)&Bs[kk][tx*4];
      const float ar[4] = {a.x, a.y, a.z, a.w};
      const float br[4] = {bq.x, bq.y, bq.z, bq.w};
      #pragma unroll
      for (int i = 0; i < 4; i++) { nsr[i] += ar[i]*ar[i]; nsc[i] += br[i]*br[i]; }
      #pragma unroll
      for (int i = 0; i < 4; i++)
        #pragma unroll
        for (int j = 0; j < 4; j++)
          acc[i][j] += ar[i] * br[j];
    }
    __syncthreads();
  }
  float* Db = D + (size_t)b * NN * NN;
  #pragma unroll
  for (int i = 0; i < 4; i++) {
    const int rr = rowBase + ty*4 + i;
    #pragma unroll
    for (int j = 0; j < 4; j++) {
      const int cc = colBase + tx*4 + j;
      const float denom = sqrtf(fmaxf(nsr[i] * nsc[j], 1e-8f));
      Db[(size_t)rr * NN + cc] = 0.5f * (1.0f - acc[i][j] / denom);
    }
  }
}

// ---------------- fused row scan + slab column scan ----------------------------
// Block = (batch, 32-row slab): row-scan 32 rows into a 64 KB LDS slab, then
// column-scan the slab in place; emit S (slab-local) + aux (slab totals).
__global__ __launch_bounds__(256) void scan_slab(
    const float* __restrict__ D, double* __restrict__ S, double* __restrict__ aux)
{
  const int s = blockIdx.x & 7;
  const int b = blockIdx.x >> 3;
  const int tid = threadIdx.x;
  const int wave = tid >> 6, lane = tid & 63;
  __shared__ double sd[32][NN];    // 64 KB
  for (int t = 0; t < 8; t++) {
    const int rl = wave * 8 + t;
    const float4 dv = *(const float4*)(D + (size_t)(b * NN + s * 32 + rl) * NN + lane * 4);
    double d0 = dv.x, d1 = dv.y, d2 = dv.z, d3 = dv.w;
    double p0 = d0, p1 = p0 + d1, p2 = p1 + d2, p3 = p2 + d3;
    double tt = p3;
    #pragma unroll
    for (int d = 1; d < 64; d <<= 1) {
      double u = __shfl_up(tt, d);
      if (lane >= d) tt += u;
    }
    const double off = tt - p3;
    sd[rl][lane*4+0] = off + p0; sd[rl][lane*4+1] = off + p1;
    sd[rl][lane*4+2] = off + p2; sd[rl][lane*4+3] = off + p3;
  }
  __syncthreads();
  const int j = tid;
  double* Sp = S + (size_t)b * NN * NN + (size_t)(s * 32) * NN + j;
  double sum = 0.0;
  for (int r = 0; r < 32; r += 8) {
    double v0 = sd[r+0][j], v1 = sd[r+1][j], v2 = sd[r+2][j], v3 = sd[r+3][j];
    double v4 = sd[r+4][j], v5 = sd[r+5][j], v6 = sd[r+6][j], v7 = sd[r+7][j];
    v0 += sum; v1 += v0; v2 += v1; v3 += v2; v4 += v3; v5 += v4; v6 += v5; v7 += v6;
    Sp[(size_t)(r+0)*NN] = v0; Sp[(size_t)(r+1)*NN] = v1;
    Sp[(size_t)(r+2)*NN] = v2; Sp[(size_t)(r+3)*NN] = v3;
    Sp[(size_t)(r+4)*NN] = v4; Sp[(size_t)(r+5)*NN] = v5;
    Sp[(size_t)(r+6)*NN] = v6; Sp[(size_t)(r+7)*NN] = v7;
    sum = v7;
  }
  aux[((size_t)b * 8 + s) * NN + j] = sum;
}

// ---------------- Ds -> A (shifted), C0 -> Cstk[0], out init -------------------
// S holds slab-local scans; cross-slab column offsets P (exclusive prefix of
// aux) are built in LDS and added on the fly: S_full[r][j] = S[r][j]+P[r>>5][j].
__global__ __launch_bounds__(256) void ds_mat(
    const double* __restrict__ S, const double* __restrict__ aux,
    float* __restrict__ A, float* __restrict__ Cstk, float* __restrict__ out)
{
  const int slab = blockIdx.x;          // 16 rows
  const int b = blockIdx.y;
  const double* Sb = S + (size_t)b * NN * NN;
  float* Ab = A + (size_t)b * NN * NN;
  const int tid = threadIdx.x;
  const int w = tid >> 6, lane = tid & 63;
  __shared__ double P[8][NN];           // 16 KB exclusive column prefixes
  __shared__ double diag[NN];
  {
    const double* ax = aux + (size_t)b * 8 * NN + tid;
    double run = 0.0;
    #pragma unroll
    for (int u = 0; u < 8; u++) { P[u][tid] = run; run += ax[(size_t)u * NN]; }
  }
  __syncthreads();
  diag[tid] = Sb[(size_t)tid * NN + tid] + P[tid >> 5][tid];
  __syncthreads();
  #pragma unroll
  for (int t = 0; t < 4; t++) {
    const int n = slab * 16 + w * 4 + t;
    const double snn = (n > 0) ? diag[n-1] : 0.0;
    const double* srow = Sb + (size_t)(n > 0 ? n-1 : 0) * NN;
    const double* Pr   = P[(n > 0 ? n-1 : 0) >> 5];
    #pragma unroll
    for (int c = 0; c < 4; c++) {
      const int jx = c * 64 + lane;
      float ds = INF;
      if (jx >= n) {
        const double sv = (n > 0) ? (srow[jx] + Pr[jx]) : 0.0;
        ds = (float)(diag[jx] - 2.0 * sv + snn);
      }
      if (jx < NN - 1) Ab[(size_t)n * NN + jx + 1] = ds;
      else             Cstk[(size_t)b * 32 * NN + n] = ds;   // Ds[n][N-1]
      if (jx == 0)     Ab[(size_t)n * NN + 0] = INF;
    }
  }
  if (slab == 0) out[b * NN + tid] = (tid == NN - 1) ? 1.0f : 0.0f;
}

// ---------------- full chain C_1..C_29, pure-A: 29 stages, 1 block/batch -------
// C_k = A (min-plus) C_{k-1}. The A2/A4 grouping (and both mp_mm dispatches) is
// gone: the C-ring LDS read volume is invariant to grouping (1 c-read per
// (row,f-step) per computed C either way) -- grouping only amortized barriers.
// 29 stages cost ~20 extra barriers (~+6 us) but save 2 kernels + 2 dispatch
// boundaries (~-24 us). Pure-A also matches the reference's fp association.
// Per thread: its quarter of A row n (16 masked float4, static idx) in VGPRs;
// cols < n+1 are INF in memory and never win the min.
constexpr int CSTR = 260;    // ring stride: 16B-aligned, breaks pow2 banks
constexpr int RING = 8;      // ring depth (power of 2)

__global__ __launch_bounds__(1024) void chain_full(
    const float* __restrict__ A, float* __restrict__ Cstk)
{
  const int b = blockIdx.x;
  const int tid = threadIdx.x;
  const int n = tid >> 2, q = tid & 3;
  __shared__ __align__(16) float cs[RING * CSTR];    // 8.3 KB
  float* Ck = Cstk + (size_t)b * 32 * NN;
  const size_t mb = (size_t)b * NN * NN;

  const int jj0 = (n + 1) & ~3;        // first float4-aligned col >= n+1
  const int La  = NN - jj0;            // floats from jj0 to end of row

  // ---- prefetch this thread's A-row quarter into registers (masked) ----------
  float4 areg[16];
  {
    const float* ar = A + mb + (size_t)n * NN + jj0;
    #pragma unroll
    for (int fi = 0; fi < 16; fi++) {
      const int f = 4 * q + 16 * fi;
      if (f < La) areg[fi] = *(const float4*)(ar + f);
      else        areg[fi] = make_float4(INF, INF, INF, INF);
    }
  }

  if (tid < NN) cs[tid] = Ck[tid];     // ring slot 0 = C0
  __syncthreads();

  for (int t = 0; t < 29; t++) {       // stage t: C_{t+1} = A (x) C_t
    float m = INF;
    const float* cb = cs + (t & (RING-1)) * CSTR + jj0 + 4 * q;
    #pragma unroll
    for (int fi = 0; fi < 16; fi++) {
      const int f = 4 * q + 16 * fi;
      if (f < La) {
        const float4 a = areg[fi];
        const float4 c = *(const float4*)(cb + 16 * fi);
        m = fminf(m, fminf(fminf(a.x + c.x, a.y + c.y),
                           fminf(a.z + c.z, a.w + c.w)));
      }
    }
    m = fminf(m, __shfl_xor(m, 1));
    m = fminf(m, __shfl_xor(m, 2));
    m = fminf(m, INF);
    if (q == 0) {
      cs[((t + 1) & (RING-1)) * CSTR + n] = m;
      Ck[(t + 1) * NN + n] = m;
    }
    __syncthreads();
  }
}

// ---------------- fused softmax: row sums (LDS) + column accumulation ----------
__global__ __launch_bounds__(256) void sm_fused(
    const float* __restrict__ A, const float* __restrict__ Cstk,
    float* __restrict__ out)
{
  const int k = blockIdx.x + 1;        // 1..29
  const int b = blockIdx.y;
  const int limit = NN - k;
  const int tid = threadIdx.x;
  const float* Ab  = A + (size_t)b * NN * NN;
  const float* Ckb = Cstk + (size_t)b * 32 * NN;
  __shared__ __align__(16) float cprev[NN];   // C_{k-1}
  __shared__ float ck[NN];                    // C_k
  __shared__ float ivh[NN];                   // 1/s per row
  cprev[tid] = Ckb[(k - 1) * NN + tid];
  ck[tid]    = Ckb[k * NN + tid];
  __syncthreads();
  const int r = tid >> 2, q = tid & 3;
  #pragma unroll
  for (int rg = 0; rg < 4; rg++) {
    const int n = rg * 64 + r;
    const float m = ck[n];
    const float* Ar = Ab + (size_t)n * NN + q * 64;
    float s = 0.f;
    if (q * 64 + 63 > n) {              // chunk has some jj > n
      #pragma unroll 4
      for (int i = 0; i < 16; i++) {
        const float4 a = *(const float4*)(Ar + i * 4);
        const int jj = q * 64 + i * 4;
        const float4 c = *(const float4*)&cprev[jj];
        s += (jj + 0 <= limit) ? __expf(m - a.x - c.x) : 0.f;
        s += (jj + 1 <= limit) ? __expf(m - a.y - c.y) : 0.f;
        s += (jj + 2 <= limit) ? __expf(m - a.z - c.z) : 0.f;
        s += (jj + 3 <= limit) ? __expf(m - a.w - c.w) : 0.f;
      }
    }
    s += __shfl_xor(s, 1);
    s += __shfl_xor(s, 2);
    if (q == 0) ivh[n] = 1.0f / s;
  }
  __syncthreads();
  const int j = tid;
  if (j < limit) {
    const float cj = cprev[j + 1];
    const int nmax = (j < limit - 1) ? j : limit - 1;
    float a = 0.0f;
    #pragma unroll 4
    for (int nr = 0; nr <= nmax; nr++)
      a += __expf(ck[nr] - Ab[(size_t)nr * NN + j + 1] - cj) * ivh[nr];
    int kmaxj = NN - 1 - j; if (kmaxj > KMAX - 1) kmaxj = KMAX - 1;
    const float cnt = (float)((j + 1) * kmaxj);
    atomicAdd(&out[b * NN + j], a / cnt);
  }
}

extern "C" void kernel_launch(void* const* d_in, const int* in_sizes, int n_in,
                              void* d_out, int out_size, void* d_ws, size_t ws_size,
                              hipStream_t stream) {
  const float* x  = (const float*)d_in[0];
  const float* W0 = (const float*)d_in[1];
  const float* b0 = (const float*)d_in[2];
  const float* W1 = (const float*)d_in[3];
  const float* b1 = (const float*)d_in[4];
  float* out = (float*)d_out;

  // ws layout (max 7 MiB + 128 KiB used; ws proven >= 8 MiB):
  //  region        lifetime
  //  h    [0,2M)   gemm1 W -> gemm2 R
  //  S    [0,4M)   scan_slab W (h dead) -> ds_mat R    (slab-local scans)
  //  D    [4M,6M)  corr_dist W -> scan_slab R
  //  A    [4M,6M)  ds_mat W (D dead) -> chain/sm R
  //  z    [6M,7M)  gemm2 W -> corr_dist R
  //  Cstk [6M,6.25M) ds_mat W (z dead) -> chain RW -> sm R
  //  aux  [7M,7M+128K) scan_slab W -> ds_mat R
  char* base = (char*)d_ws;
  float*  h    = (float*)(base);
  double* S    = (double*)(base);
  float*  D    = (float*)(base + (4u << 20));
  float*  A    = (float*)(base + (4u << 20));
  float*  z    = (float*)(base + (6u << 20));
  float*  Cstk = (float*)(base + (6u << 20));
  double* aux  = (double*)(base + (7u << 20));

  gemm_bias_act<<<dim3(F1/32, ROWS/64), 256, 0, stream>>>(x, W0, b0, h, ROWS, F1, F0, 1);
  gemm_bias_act<<<dim3(F2/32, ROWS/64), 256, 0, stream>>>(h, W1, b1, z, ROWS, F2, F1, 0);
  corr_dist<<<dim3(NN/64, NN/64, NB), 256, 0, stream>>>(z, D);
  scan_slab<<<dim3(NB*8), 256, 0, stream>>>(D, S, aux);
  ds_mat<<<dim3(16, NB), 256, 0, stream>>>(S, aux, A, Cstk, out);
  chain_full<<<dim3(NB), 1024, 0, stream>>>(A, Cstk);
  sm_fused<<<dim3(KMAX-1, NB), 256, 0, stream>>>(A, Cstk, out);
}